// Round 10
// baseline (495.465 us; speedup 1.0000x reference)
//
#include <hip/hip_runtime.h>
#include <hip/hip_fp16.h>

// HyperConv: out = (x + Ax + A^2x + A^3x) / 4, A in COO (rows, cols, vals).
// N=100000 items, E=800000 edges, D=64 features, fp32 in/out.
//
// Round 10: XCD-local feature chunking. SpMM doesn't mix feature dims, so
// split D=64 into 8 chunks of 8 feats (16B/row fp16, 1.6MB/chunk) stored
// chunk-major, and pin chunk f to XCD f via blockIdx%8 (round-robin dispatch
// heuristic; correctness-neutral). Each XCD's random gathers then hit a
// 1.6MB operand resident in its own 4MB L2 instead of missing to L3 ~70% of
// the time (the measured invariant across R4-R9: ~38us/layer, 2.5x byte
// bound). Metadata = compact CSR (rowptr + edges), streamed nontemporal once
// per chunk (8 x 6.4MB/layer ~ 8us). part2 rewritten: LDS counts -> wave
// scan -> bin-local compact scatter (edges cached in LDS).

#define NI 100000
#define NE 800000
#define DD 64
#define NCH 8                         // feature chunks (== XCDs)
#define CF  8                         // features per chunk

#define RPB  512                      // rows per bin
#define BINS ((NI + RPB - 1) / RPB)   // 196
#define EPB  1024                     // edges per part1 block
#define P1B  ((NE + EPB - 1) / EPB)   // 782
#define CAP  5120                     // per-bin capacity (mean 4096, 16-sigma)

// ---------------------------------------------------------------------------
// part1: bin edges by row>>9 with block-contiguous runs (L2 line-merged).
// payload: .x = (row&511)<<17 | col, .y = val bits
// ---------------------------------------------------------------------------
__global__ __launch_bounds__(256) void part1_k(const int* __restrict__ rows,
                                               const int* __restrict__ cols,
                                               const float* __restrict__ vals,
                                               int* __restrict__ bin_cnt,
                                               int2* __restrict__ binned) {
    __shared__ int hist[BINS], base[BINS], cur[BINS];
    int t = threadIdx.x;
    for (int i = t; i < BINS; i += 256) hist[i] = 0;
    __syncthreads();
    int e0 = blockIdx.x * EPB;
    for (int i = t; i < EPB; i += 256) {
        int e = e0 + i;
        if (e < NE) atomicAdd(&hist[rows[e] >> 9], 1);
    }
    __syncthreads();
    for (int i = t; i < BINS; i += 256) {
        int c = hist[i];
        base[i] = c ? atomicAdd(&bin_cnt[i], c) : 0;
        cur[i] = 0;
    }
    __syncthreads();
    for (int i = t; i < EPB; i += 256) {
        int e = e0 + i;
        if (e < NE) {
            int r = rows[e];
            int b = r >> 9;
            int pos = base[b] + atomicAdd(&cur[b], 1);
            if (pos < CAP)
                binned[(size_t)b * CAP + pos] =
                    make_int2(((r & 511) << 17) | cols[e], __float_as_int(vals[e]));
        }
    }
}

// ---------------------------------------------------------------------------
// part2: one block per bin -> compact CSR. LDS: per-row counts, wave-0 scan
// (exclusive, 512 entries), edge cache (CAP x 8B = 40KB), then bin-local
// compact scatter. Emits global rowptr (binbase = prefix of bin totals).
// ---------------------------------------------------------------------------
__global__ __launch_bounds__(256) void part2_k(const int* __restrict__ bin_cnt,
                                               const int2* __restrict__ binned,
                                               int2* __restrict__ edges,
                                               int* __restrict__ rowptr) {
    __shared__ int cur[RPB], off[RPB];
    __shared__ long long ecache[CAP];
    __shared__ int bb;
    int t = threadIdx.x;
    int b = blockIdx.x;

    for (int i = t; i < RPB; i += 256) cur[i] = 0;
    if (t < BINS) off[t] = min(bin_cnt[t], CAP);   // temp: per-bin totals
    __syncthreads();
    if (t == 0) {
        int s = 0;
        for (int i = 0; i < b; i++) s += off[i];
        bb = s;
    }
    int cnt = min(bin_cnt[b], CAP);
    const int2* src = binned + (size_t)b * CAP;
    __syncthreads();                               // bb set; off temp consumed
    for (int i = t; i < cnt; i += 256) {
        int2 e = src[i];
        atomicAdd(&cur[e.x >> 17], 1);
        ecache[i] = ((long long)e.y << 32) | (unsigned int)e.x;
    }
    __syncthreads();
    if (t < 64) {                                  // wave-0 scan of 512 counts
        int base_i = t * 8;
        int loc[8];
        int s = 0;
        #pragma unroll
        for (int k = 0; k < 8; k++) { loc[k] = s; s += cur[base_i + k]; }
        int excl = s;
        #pragma unroll
        for (int d = 1; d < 64; d <<= 1) {
            int v = __shfl_up(excl, d, 64);
            if (t >= d) excl += v;
        }
        excl -= s;                                 // exclusive over lane totals
        #pragma unroll
        for (int k = 0; k < 8; k++) off[base_i + k] = excl + loc[k];
    }
    __syncthreads();
    for (int i = t; i < RPB; i += 256) {
        int r = b * RPB + i;
        if (r < NI) rowptr[r] = bb + off[i];
        cur[i] = 0;
    }
    if (b == BINS - 1 && t == 0) rowptr[NI] = bb + cnt;
    __syncthreads();
    for (int i = t; i < cnt; i += 256) {
        long long e = ecache[i];
        int lo = (int)e;
        int rl = (lo >> 17) & 511;
        int pos = bb + off[rl] + atomicAdd(&cur[rl], 1);
        edges[pos] = make_int2(lo & 0x1FFFF, (int)(e >> 32));
    }
}

// ---------------------------------------------------------------------------
// convert: x (row-major fp32) -> xh (chunk-major fp16): xh[c][r][0..7]
// ---------------------------------------------------------------------------
__global__ __launch_bounds__(256) void convert_k(const float* __restrict__ x,
                                                 __half* __restrict__ xh) {
    int r = blockIdx.x * 256 + threadIdx.x;
    int c = blockIdx.y;
    if (r < NI) {
        const float4* xp = (const float4*)(x + (size_t)r * DD + c * CF);
        float4 xa = xp[0], xb = xp[1];
        uint4 o;
        __half2 h;
        h = __floats2half2_rn(xa.x, xa.y); o.x = *(unsigned int*)&h;
        h = __floats2half2_rn(xa.z, xa.w); o.y = *(unsigned int*)&h;
        h = __floats2half2_rn(xb.x, xb.y); o.z = *(unsigned int*)&h;
        h = __floats2half2_rn(xb.w, xb.w); o.w = *(unsigned int*)&h;  // fixed below
        h = __floats2half2_rn(xb.z, xb.w); o.w = *(unsigned int*)&h;
        *(uint4*)(xh + (size_t)c * NI * CF + (size_t)r * CF) = o;
    }
}

// ---------------------------------------------------------------------------
// Chunked gather SpMM: 1 lane = 1 output row x 1 chunk (8 feats, 16B gather).
// chunk = blockIdx % 8 (XCD affinity), rowblk = blockIdx / 8.
// MODE 0/1: nxt(half, chunk-major) = A * xin(half, chunk-major)
// MODE 2:   outp(f32, row-major) = (x0 + s1 + xin + A*xin) * 0.25  (xin==s2)
// ---------------------------------------------------------------------------
template <int MODE>
__global__ __launch_bounds__(256) void spmm_k(const int* __restrict__ rowptr,
                                              const long long* __restrict__ edges,
                                              const __half* __restrict__ xin,
                                              __half* __restrict__ nxt,
                                              const float* __restrict__ x0,
                                              const __half* __restrict__ s1,
                                              float* __restrict__ outp) {
    int chunk  = blockIdx.x & 7;
    int rowblk = blockIdx.x >> 3;
    int r = rowblk * 256 + threadIdx.x;
    bool act = (r < NI);
    int beg = act ? rowptr[r] : 0;
    int end = act ? rowptr[r + 1] : 0;
    const __half* xc = xin + (size_t)chunk * NI * CF;

    float a0 = 0.f, a1 = 0.f, a2 = 0.f, a3 = 0.f;
    float a4 = 0.f, a5 = 0.f, a6 = 0.f, a7 = 0.f;

    for (int j = beg; j < end; ++j) {
        long long e = __builtin_nontemporal_load(edges + j);
        int col = (int)e;                          // low 32 = col
        float v = __int_as_float((int)(e >> 32));
        uint4 g = *(const uint4*)(xc + (size_t)col * CF);
        float2 f;
        f = __half22float2(*(__half2*)&g.x); a0 += v * f.x; a1 += v * f.y;
        f = __half22float2(*(__half2*)&g.y); a2 += v * f.x; a3 += v * f.y;
        f = __half22float2(*(__half2*)&g.z); a4 += v * f.x; a5 += v * f.y;
        f = __half22float2(*(__half2*)&g.w); a6 += v * f.x; a7 += v * f.y;
    }

    if (!act) return;
    size_t co = (size_t)chunk * NI * CF + (size_t)r * CF;
    if (MODE == 2) {
        const float4* xp = (const float4*)(x0 + (size_t)r * DD + chunk * CF);
        float4 xa = xp[0], xb = xp[1];
        uint4 s1u = *(const uint4*)(s1 + co);
        uint4 s2u = *(const uint4*)(xin + co);
        float4 oa, ob;
        float2 f1, f2;
        f1 = __half22float2(*(__half2*)&s1u.x); f2 = __half22float2(*(__half2*)&s2u.x);
        oa.x = (xa.x + f1.x + f2.x + a0) * 0.25f;
        oa.y = (xa.y + f1.y + f2.y + a1) * 0.25f;
        f1 = __half22float2(*(__half2*)&s1u.y); f2 = __half22float2(*(__half2*)&s2u.y);
        oa.z = (xa.z + f1.x + f2.x + a2) * 0.25f;
        oa.w = (xa.w + f1.y + f2.y + a3) * 0.25f;
        f1 = __half22float2(*(__half2*)&s1u.z); f2 = __half22float2(*(__half2*)&s2u.z);
        ob.x = (xb.x + f1.x + f2.x + a4) * 0.25f;
        ob.y = (xb.y + f1.y + f2.y + a5) * 0.25f;
        f1 = __half22float2(*(__half2*)&s1u.w); f2 = __half22float2(*(__half2*)&s2u.w);
        ob.z = (xb.z + f1.x + f2.x + a6) * 0.25f;
        ob.w = (xb.w + f1.y + f2.y + a7) * 0.25f;
        float4* op = (float4*)(outp + (size_t)r * DD + chunk * CF);
        op[0] = oa;
        op[1] = ob;
    } else {
        uint4 o;
        __half2 h;
        h = __floats2half2_rn(a0, a1); o.x = *(unsigned int*)&h;
        h = __floats2half2_rn(a2, a3); o.y = *(unsigned int*)&h;
        h = __floats2half2_rn(a4, a5); o.z = *(unsigned int*)&h;
        h = __floats2half2_rn(a6, a7); o.w = *(unsigned int*)&h;
        *(uint4*)(nxt + co) = o;
    }
}

// ===========================================================================
// Fallback (round-2 CSR path, fp32, known-good) if ws_size can't fit
// ===========================================================================
#define NB ((NI + 255) / 256)

__global__ __launch_bounds__(256) void init_k(const float4* __restrict__ x,
                                              float4* __restrict__ cur,
                                              float4* __restrict__ acc, int n4) {
    int i = blockIdx.x * 256 + threadIdx.x;
    if (i < n4) { float4 v = x[i]; cur[i] = v; acc[i] = v; }
}

__global__ __launch_bounds__(256) void hist_k(const int* __restrict__ rows,
                                              int* __restrict__ counts) {
    int e = blockIdx.x * 256 + threadIdx.x;
    if (e < NE) atomicAdd(&counts[rows[e]], 1);
}

__global__ __launch_bounds__(256) void scan1_k(const int* __restrict__ counts,
                                               int* __restrict__ bsum) {
    __shared__ int s[256];
    int t = threadIdx.x;
    int i = blockIdx.x * 256 + t;
    s[t] = (i < NI) ? counts[i] : 0;
    __syncthreads();
    for (int off = 128; off > 0; off >>= 1) {
        if (t < off) s[t] += s[t + off];
        __syncthreads();
    }
    if (t == 0) bsum[blockIdx.x] = s[0];
}

__global__ __launch_bounds__(512) void scan2_k(int* __restrict__ bsum) {
    __shared__ int s[512];
    int t = threadIdx.x;
    int v = (t < NB) ? bsum[t] : 0;
    s[t] = v;
    __syncthreads();
    for (int off = 1; off < 512; off <<= 1) {
        int tmp = (t >= off) ? s[t - off] : 0;
        __syncthreads();
        s[t] += tmp;
        __syncthreads();
    }
    if (t < NB) bsum[t] = s[t] - v;
}

__global__ __launch_bounds__(256) void scan3_k(const int* __restrict__ counts,
                                               const int* __restrict__ bsum,
                                               int* __restrict__ rowptr) {
    __shared__ int s[256];
    int t = threadIdx.x;
    int i = blockIdx.x * 256 + t;
    int v = (i < NI) ? counts[i] : 0;
    s[t] = v;
    __syncthreads();
    for (int off = 1; off < 256; off <<= 1) {
        int tmp = (t >= off) ? s[t - off] : 0;
        __syncthreads();
        s[t] += tmp;
        __syncthreads();
    }
    int excl = s[t] - v + bsum[blockIdx.x];
    if (i < NI) rowptr[i] = excl;
    if (i == NI - 1) rowptr[NI] = excl + v;
}

__global__ __launch_bounds__(256) void scatter_k(const int* __restrict__ rows,
                                                 const int* __restrict__ cols,
                                                 const float* __restrict__ vals,
                                                 const int* __restrict__ rowptr,
                                                 int* __restrict__ fillc,
                                                 int2* __restrict__ edges) {
    int e = blockIdx.x * 256 + threadIdx.x;
    if (e < NE) {
        int r = rows[e];
        int pos = rowptr[r] + atomicAdd(&fillc[r], 1);
        edges[pos] = make_int2(cols[e], __float_as_int(vals[e]));
    }
}

__global__ __launch_bounds__(256) void spmm_csr_k(const int* __restrict__ rowptr,
                                                  const int2* __restrict__ edges,
                                                  const float* __restrict__ x,
                                                  float* __restrict__ nxt,
                                                  float* __restrict__ acc,
                                                  int last) {
    int r = __builtin_amdgcn_readfirstlane(blockIdx.x * 4 + (threadIdx.x >> 6));
    int lane = threadIdx.x & 63;
    int beg = rowptr[r];
    int end = rowptr[r + 1];
    float s = 0.f;
    int j = beg;
    for (; j + 3 < end; j += 4) {
        int2 e0 = edges[j], e1 = edges[j + 1], e2 = edges[j + 2], e3 = edges[j + 3];
        float g0 = x[(size_t)e0.x * DD + lane];
        float g1 = x[(size_t)e1.x * DD + lane];
        float g2 = x[(size_t)e2.x * DD + lane];
        float g3 = x[(size_t)e3.x * DD + lane];
        s += __int_as_float(e0.y) * g0; s += __int_as_float(e1.y) * g1;
        s += __int_as_float(e2.y) * g2; s += __int_as_float(e3.y) * g3;
    }
    for (; j < end; ++j) {
        int2 e = edges[j];
        s += __int_as_float(e.y) * x[(size_t)e.x * DD + lane];
    }
    size_t o = (size_t)r * DD + lane;
    if (last) acc[o] = (acc[o] + s) * 0.25f;
    else { nxt[o] = s; acc[o] += s; }
}

extern "C" void kernel_launch(void* const* d_in, const int* in_sizes, int n_in,
                              void* d_out, int out_size, void* d_ws, size_t ws_size,
                              hipStream_t stream) {
    const int*   rows = (const int*)d_in[0];
    const int*   cols = (const int*)d_in[1];
    const float* vals = (const float*)d_in[2];
    const float* x    = (const float*)d_in[3];
    float* outp = (float*)d_out;

    const size_t fbuf = (size_t)NI * DD * sizeof(float);    // 25.6 MB
    const size_t hbuf = (size_t)NI * DD * sizeof(__half);   // 12.8 MB

    char* wsp = (char*)d_ws;

    // layout: xh | s1h | s2h (chunk-major halves) | binned | edges | rowptr |
    //         bin_cnt
    size_t off_xh     = 0;
    size_t off_s1     = off_xh + hbuf;
    size_t off_s2     = off_s1 + hbuf;
    size_t off_binned = off_s2 + hbuf;
    size_t off_edges  = off_binned + (size_t)BINS * CAP * 8;
    size_t off_rowptr = off_edges + (size_t)NE * 8;
    size_t off_bcnt   = off_rowptr + ((size_t)NI + 2) * 4;
    size_t need       = off_bcnt + (size_t)BINS * 4;

    if (ws_size >= need) {
        __half* xh      = (__half*)(wsp + off_xh);
        __half* s1h     = (__half*)(wsp + off_s1);
        __half* s2h     = (__half*)(wsp + off_s2);
        int2*   binned  = (int2*)(wsp + off_binned);
        int2*   edges   = (int2*)(wsp + off_edges);
        int*    rowptr  = (int*)(wsp + off_rowptr);
        int*    bin_cnt = (int*)(wsp + off_bcnt);

        hipMemsetAsync(bin_cnt, 0, BINS * sizeof(int), stream);
        part1_k<<<P1B, 256, 0, stream>>>(rows, cols, vals, bin_cnt, binned);
        part2_k<<<BINS, 256, 0, stream>>>(bin_cnt, binned, edges, rowptr);
        convert_k<<<dim3((NI + 255) / 256, NCH), 256, 0, stream>>>(x, xh);

        const int grid_spmm = ((NI + 255) / 256) * NCH;   // 391*8 = 3128
        spmm_k<0><<<grid_spmm, 256, 0, stream>>>(rowptr, (const long long*)edges,
                                                 xh, s1h, nullptr, nullptr, nullptr);
        spmm_k<1><<<grid_spmm, 256, 0, stream>>>(rowptr, (const long long*)edges,
                                                 s1h, s2h, nullptr, nullptr, nullptr);
        spmm_k<2><<<grid_spmm, 256, 0, stream>>>(rowptr, (const long long*)edges,
                                                 s2h, nullptr, x, s1h, outp);
        return;
    }

    // ---- fallback: round-2 CSR path (fp32) ----
    const int n4        = NI * DD / 4;
    const int grid_elem = (n4 + 255) / 256;
    const int grid_edge = (NE + 255) / 256;
    const int grid_csr  = NI / 4;

    float* bufA   = (float*)wsp;
    float* bufB   = (float*)(wsp + fbuf);
    int2*  edgesF = (int2*)(wsp + 2 * fbuf);
    int*   rowptr = (int*)(wsp + 2 * fbuf + (size_t)NE * 8);
    int*   counts = rowptr + (NI + 1);
    int*   bsum   = counts + NI;

    hipMemsetAsync(counts, 0, NI * sizeof(int), stream);
    hist_k<<<grid_edge, 256, 0, stream>>>(rows, counts);
    scan1_k<<<NB, 256, 0, stream>>>(counts, bsum);
    scan2_k<<<1, 512, 0, stream>>>(bsum);
    scan3_k<<<NB, 256, 0, stream>>>(counts, bsum, rowptr);
    hipMemsetAsync(counts, 0, NI * sizeof(int), stream);
    scatter_k<<<grid_edge, 256, 0, stream>>>(rows, cols, vals, rowptr, counts, edgesF);
    init_k<<<grid_elem, 256, 0, stream>>>((const float4*)x, (float4*)bufA,
                                          (float4*)outp, n4);
    spmm_csr_k<<<grid_csr, 256, 0, stream>>>(rowptr, edgesF, bufA, bufB, outp, 0);
    spmm_csr_k<<<grid_csr, 256, 0, stream>>>(rowptr, edgesF, bufB, bufA, outp, 0);
    spmm_csr_k<<<grid_csr, 256, 0, stream>>>(rowptr, edgesF, bufA, bufB, outp, 1);
}

// Round 11
// 185.696 us; speedup vs baseline: 2.6681x; 2.6681x over previous
//
#include <hip/hip_runtime.h>
#include <hip/hip_fp16.h>

// HyperConv: out = (x + Ax + A^2x + A^3x) / 4, A in COO (rows, cols, vals).
// N=100000 items, E=800000 edges, D=64 features, fp32 in/out.
//
// Round 11: revert round-10's XCD feature chunking (regression 495us:
// 16B/row chunk-major gathers used 1/4 of each 64B line -> FETCH 257MB/layer,
// pure L2-miss-traffic bound; blockIdx%8 XCD affinity produced no residency
// win). Restore the round-7/9 best (186-187us):
//  - part1/part2 two-pass partition into padded row buckets (L2 line-merged)
//  - fp16 activations (128B row = full line utilization), fp32 accumulate
//  - 8-rows-per-wave spmm, dwordx4 gathers, reg-preloaded shfl-bcast metadata
// Session evidence: 5 spmm structures all ~38us/layer (2.5x byte bound);
// byte-halving sublinear; sort-locality negative; XCD pinning negative.
// -> random-line L2-miss service is the structural limit for this op shape.

#define NI 100000
#define NE 800000
#define DD 64

#define RPB  512                      // rows per bin
#define BINS ((NI + RPB - 1) / RPB)   // 196
#define EPB  1024                     // edges per part1 block
#define P1B  ((NE + EPB - 1) / EPB)   // 782
#define CAP  5120                     // per-bin capacity (mean 4096, 16-sigma)
#define BC   32                       // bucket capacity per row (max deg ~22)

// ---------------------------------------------------------------------------
// part1: bin edges by row>>9 with block-contiguous runs (L2 line-merged).
// payload: .x = (row&511)<<17 | col, .y = val bits
// ---------------------------------------------------------------------------
__global__ __launch_bounds__(256) void part1_k(const int* __restrict__ rows,
                                               const int* __restrict__ cols,
                                               const float* __restrict__ vals,
                                               int* __restrict__ bin_cnt,
                                               int2* __restrict__ binned) {
    __shared__ int hist[BINS], base[BINS], cur[BINS];
    int t = threadIdx.x;
    for (int i = t; i < BINS; i += 256) hist[i] = 0;
    __syncthreads();
    int e0 = blockIdx.x * EPB;
    for (int i = t; i < EPB; i += 256) {
        int e = e0 + i;
        if (e < NE) atomicAdd(&hist[rows[e] >> 9], 1);
    }
    __syncthreads();
    for (int i = t; i < BINS; i += 256) {
        int c = hist[i];
        base[i] = c ? atomicAdd(&bin_cnt[i], c) : 0;
        cur[i] = 0;
    }
    __syncthreads();
    for (int i = t; i < EPB; i += 256) {
        int e = e0 + i;
        if (e < NE) {
            int r = rows[e];
            int b = r >> 9;
            int pos = base[b] + atomicAdd(&cur[b], 1);
            if (pos < CAP)
                binned[(size_t)b * CAP + pos] =
                    make_int2(((r & 511) << 17) | cols[e], __float_as_int(vals[e]));
        }
    }
}

// ---------------------------------------------------------------------------
// part2: one block per bin; bin-local scatter into row buckets; pads each
// row's bucket to EVEN degree with a zero edge so the spmm j-loop steps by 2.
// ---------------------------------------------------------------------------
__global__ __launch_bounds__(256) void part2_k(const int* __restrict__ bin_cnt,
                                               const int2* __restrict__ binned,
                                               int2* __restrict__ bucket,
                                               int* __restrict__ fill) {
    __shared__ int cur[RPB];
    int t = threadIdx.x;
    int b = blockIdx.x;
    for (int i = t; i < RPB; i += 256) cur[i] = 0;
    __syncthreads();
    int cnt = bin_cnt[b];
    if (cnt > CAP) cnt = CAP;
    const int2* src = binned + (size_t)b * CAP;
    for (int i = t; i < cnt; i += 256) {
        int2 e = src[i];
        int rl = e.x >> 17;
        int pos = atomicAdd(&cur[rl], 1);
        if (pos < BC)
            bucket[((size_t)b * RPB + rl) * BC + pos] = make_int2(e.x & 0x1FFFF, e.y);
    }
    __syncthreads();
    for (int i = t; i < RPB; i += 256) {
        int r = b * RPB + i;
        if (r < NI) {
            int c = (cur[i] < BC) ? cur[i] : BC;
            if (c & 1) {
                bucket[((size_t)b * RPB + i) * BC + c] = make_int2(0, 0);
                c++;
            }
            fill[r] = c;
        }
    }
}

// ---------------------------------------------------------------------------
// convert: xh = (half)x
// ---------------------------------------------------------------------------
__global__ __launch_bounds__(256) void convert_k(const float4* __restrict__ x,
                                                 __half* __restrict__ xh, int n4) {
    int i = blockIdx.x * 256 + threadIdx.x;
    if (i < n4) {
        float4 v = x[i];
        __half2* dst = (__half2*)(xh + (size_t)i * 4);
        dst[0] = __floats2half2_rn(v.x, v.y);
        dst[1] = __floats2half2_rn(v.z, v.w);
    }
}

// ---------------------------------------------------------------------------
// 8-rows-per-wave gather SpMM with register-preloaded metadata.
// Block = 256 thr = 4 waves = 32 rows. grp = row in wave, ll = feature octet.
// MODE 0/1: nxt(half) = A * xin(half)
// MODE 2:   outp(f32) = (x0 + s1 + xin + A*xin) * 0.25   (xin == s2)
// ---------------------------------------------------------------------------
template <int MODE>
__global__ __launch_bounds__(256) void spmm_k(const int* __restrict__ fill,
                                              const int2* __restrict__ bucket,
                                              const __half* __restrict__ xin,
                                              __half* __restrict__ nxt,
                                              const float* __restrict__ x0,
                                              const __half* __restrict__ s1,
                                              float* __restrict__ outp) {
    int tid  = threadIdx.x;
    int lane = tid & 63;
    int grp  = lane >> 3;                       // row within wave (0..7)
    int ll   = lane & 7;                        // feature octet index
    int r    = blockIdx.x * 32 + (tid >> 6) * 8 + grp;
    int deg  = fill[r];                         // even (padded), <= BC
    const int2* ep = bucket + (size_t)r * BC;

    int wmax = deg;
    wmax = max(wmax, __shfl_xor(wmax, 8, 64));
    wmax = max(wmax, __shfl_xor(wmax, 16, 64));
    wmax = max(wmax, __shfl_xor(wmax, 32, 64));

    uint4 q0 = *(const uint4*)(ep + 2 * ll);
    uint4 q1 = make_uint4(0u, 0u, 0u, 0u);
    if (wmax > 16) q1 = *(const uint4*)(ep + 16 + 2 * ll);

    float a0 = 0.f, a1 = 0.f, a2 = 0.f, a3 = 0.f;
    float a4 = 0.f, a5 = 0.f, a6 = 0.f, a7 = 0.f;

    for (int j = 0; j < wmax; j += 2) {
        int src = (lane & 56) | ((j >> 1) & 7);
        uint4 q = (j < 16) ? q0 : q1;
        int c0  = __shfl((int)q.x, src, 64);
        int v0i = __shfl((int)q.y, src, 64);
        int c1  = __shfl((int)q.z, src, 64);
        int v1i = __shfl((int)q.w, src, 64);
        if (j < deg) {
            uint4 g0 = *(const uint4*)(xin + (size_t)c0 * DD + 8 * ll);
            uint4 g1 = *(const uint4*)(xin + (size_t)c1 * DD + 8 * ll);
            float v0 = __int_as_float(v0i);
            float v1 = __int_as_float(v1i);
            float2 f;
            f = __half22float2(*(__half2*)&g0.x); a0 += v0 * f.x; a1 += v0 * f.y;
            f = __half22float2(*(__half2*)&g0.y); a2 += v0 * f.x; a3 += v0 * f.y;
            f = __half22float2(*(__half2*)&g0.z); a4 += v0 * f.x; a5 += v0 * f.y;
            f = __half22float2(*(__half2*)&g0.w); a6 += v0 * f.x; a7 += v0 * f.y;
            f = __half22float2(*(__half2*)&g1.x); a0 += v1 * f.x; a1 += v1 * f.y;
            f = __half22float2(*(__half2*)&g1.y); a2 += v1 * f.x; a3 += v1 * f.y;
            f = __half22float2(*(__half2*)&g1.z); a4 += v1 * f.x; a5 += v1 * f.y;
            f = __half22float2(*(__half2*)&g1.w); a6 += v1 * f.x; a7 += v1 * f.y;
        }
    }

    if (MODE == 2) {
        size_t fo = (size_t)r * DD + 8 * ll;
        const float4* xp = (const float4*)(x0 + fo);
        float4 xa = xp[0], xb = xp[1];
        uint4 s1u = *(const uint4*)(s1 + fo);
        uint4 s2u = *(const uint4*)(xin + fo);
        float4 oa, ob;
        float2 f1, f2;
        f1 = __half22float2(*(__half2*)&s1u.x); f2 = __half22float2(*(__half2*)&s2u.x);
        oa.x = (xa.x + f1.x + f2.x + a0) * 0.25f;
        oa.y = (xa.y + f1.y + f2.y + a1) * 0.25f;
        f1 = __half22float2(*(__half2*)&s1u.y); f2 = __half22float2(*(__half2*)&s2u.y);
        oa.z = (xa.z + f1.x + f2.x + a2) * 0.25f;
        oa.w = (xa.w + f1.y + f2.y + a3) * 0.25f;
        f1 = __half22float2(*(__half2*)&s1u.z); f2 = __half22float2(*(__half2*)&s2u.z);
        ob.x = (xb.x + f1.x + f2.x + a4) * 0.25f;
        ob.y = (xb.y + f1.y + f2.y + a5) * 0.25f;
        f1 = __half22float2(*(__half2*)&s1u.w); f2 = __half22float2(*(__half2*)&s2u.w);
        ob.z = (xb.z + f1.x + f2.x + a6) * 0.25f;
        ob.w = (xb.w + f1.y + f2.y + a7) * 0.25f;
        float4* op = (float4*)(outp + fo);
        op[0] = oa;
        op[1] = ob;
    } else {
        uint4 o;
        __half2 h;
        h = __floats2half2_rn(a0, a1); o.x = *(uint*)&h;
        h = __floats2half2_rn(a2, a3); o.y = *(uint*)&h;
        h = __floats2half2_rn(a4, a5); o.z = *(uint*)&h;
        h = __floats2half2_rn(a6, a7); o.w = *(uint*)&h;
        *(uint4*)(nxt + (size_t)r * DD + 8 * ll) = o;
    }
}

// ===========================================================================
// Fallback (round-2 CSR path, fp32, known-good) if ws_size can't fit
// ===========================================================================
#define NB ((NI + 255) / 256)

__global__ __launch_bounds__(256) void init_k(const float4* __restrict__ x,
                                              float4* __restrict__ cur,
                                              float4* __restrict__ acc, int n4) {
    int i = blockIdx.x * 256 + threadIdx.x;
    if (i < n4) { float4 v = x[i]; cur[i] = v; acc[i] = v; }
}

__global__ __launch_bounds__(256) void hist_k(const int* __restrict__ rows,
                                              int* __restrict__ counts) {
    int e = blockIdx.x * 256 + threadIdx.x;
    if (e < NE) atomicAdd(&counts[rows[e]], 1);
}

__global__ __launch_bounds__(256) void scan1_k(const int* __restrict__ counts,
                                               int* __restrict__ bsum) {
    __shared__ int s[256];
    int t = threadIdx.x;
    int i = blockIdx.x * 256 + t;
    s[t] = (i < NI) ? counts[i] : 0;
    __syncthreads();
    for (int off = 128; off > 0; off >>= 1) {
        if (t < off) s[t] += s[t + off];
        __syncthreads();
    }
    if (t == 0) bsum[blockIdx.x] = s[0];
}

__global__ __launch_bounds__(512) void scan2_k(int* __restrict__ bsum) {
    __shared__ int s[512];
    int t = threadIdx.x;
    int v = (t < NB) ? bsum[t] : 0;
    s[t] = v;
    __syncthreads();
    for (int off = 1; off < 512; off <<= 1) {
        int tmp = (t >= off) ? s[t - off] : 0;
        __syncthreads();
        s[t] += tmp;
        __syncthreads();
    }
    if (t < NB) bsum[t] = s[t] - v;
}

__global__ __launch_bounds__(256) void scan3_k(const int* __restrict__ counts,
                                               const int* __restrict__ bsum,
                                               int* __restrict__ rowptr) {
    __shared__ int s[256];
    int t = threadIdx.x;
    int i = blockIdx.x * 256 + t;
    int v = (i < NI) ? counts[i] : 0;
    s[t] = v;
    __syncthreads();
    for (int off = 1; off < 256; off <<= 1) {
        int tmp = (t >= off) ? s[t - off] : 0;
        __syncthreads();
        s[t] += tmp;
        __syncthreads();
    }
    int excl = s[t] - v + bsum[blockIdx.x];
    if (i < NI) rowptr[i] = excl;
    if (i == NI - 1) rowptr[NI] = excl + v;
}

__global__ __launch_bounds__(256) void scatter_k(const int* __restrict__ rows,
                                                 const int* __restrict__ cols,
                                                 const float* __restrict__ vals,
                                                 const int* __restrict__ rowptr,
                                                 int* __restrict__ fillc,
                                                 int2* __restrict__ edges) {
    int e = blockIdx.x * 256 + threadIdx.x;
    if (e < NE) {
        int r = rows[e];
        int pos = rowptr[r] + atomicAdd(&fillc[r], 1);
        edges[pos] = make_int2(cols[e], __float_as_int(vals[e]));
    }
}

__global__ __launch_bounds__(256) void spmm_csr_k(const int* __restrict__ rowptr,
                                                  const int2* __restrict__ edges,
                                                  const float* __restrict__ x,
                                                  float* __restrict__ nxt,
                                                  float* __restrict__ acc,
                                                  int last) {
    int r = __builtin_amdgcn_readfirstlane(blockIdx.x * 4 + (threadIdx.x >> 6));
    int lane = threadIdx.x & 63;
    int beg = rowptr[r];
    int end = rowptr[r + 1];
    float s = 0.f;
    int j = beg;
    for (; j + 3 < end; j += 4) {
        int2 e0 = edges[j], e1 = edges[j + 1], e2 = edges[j + 2], e3 = edges[j + 3];
        float g0 = x[(size_t)e0.x * DD + lane];
        float g1 = x[(size_t)e1.x * DD + lane];
        float g2 = x[(size_t)e2.x * DD + lane];
        float g3 = x[(size_t)e3.x * DD + lane];
        s += __int_as_float(e0.y) * g0; s += __int_as_float(e1.y) * g1;
        s += __int_as_float(e2.y) * g2; s += __int_as_float(e3.y) * g3;
    }
    for (; j < end; ++j) {
        int2 e = edges[j];
        s += __int_as_float(e.y) * x[(size_t)e.x * DD + lane];
    }
    size_t o = (size_t)r * DD + lane;
    if (last) acc[o] = (acc[o] + s) * 0.25f;
    else { nxt[o] = s; acc[o] += s; }
}

extern "C" void kernel_launch(void* const* d_in, const int* in_sizes, int n_in,
                              void* d_out, int out_size, void* d_ws, size_t ws_size,
                              hipStream_t stream) {
    const int*   rows = (const int*)d_in[0];
    const int*   cols = (const int*)d_in[1];
    const float* vals = (const float*)d_in[2];
    const float* x    = (const float*)d_in[3];
    float* outp = (float*)d_out;

    const size_t fbuf  = (size_t)NI * DD * sizeof(float);    // 25.6 MB
    const size_t hbuf  = (size_t)NI * DD * sizeof(__half);   // 12.8 MB
    const int    n4        = NI * DD / 4;
    const int    grid_elem = (n4 + 255) / 256;

    char* wsp = (char*)d_ws;

    // layout: xh | s1h | s2h | bucket(NI*BC*8=25.6MB) | binned(BINS*CAP*8) |
    //         fill(NI*4) | bin_cnt(BINS*4)
    size_t off_xh     = 0;
    size_t off_s1     = off_xh + hbuf;
    size_t off_s2     = off_s1 + hbuf;
    size_t off_bucket = off_s2 + hbuf;
    size_t off_binned = off_bucket + (size_t)NI * BC * 8;
    size_t off_fill   = off_binned + (size_t)BINS * CAP * 8;
    size_t off_bcnt   = off_fill + (size_t)NI * 4;
    size_t need       = off_bcnt + (size_t)BINS * 4;

    if (ws_size >= need) {
        __half* xh      = (__half*)(wsp + off_xh);
        __half* s1h     = (__half*)(wsp + off_s1);
        __half* s2h     = (__half*)(wsp + off_s2);
        int2*   bucket  = (int2*)(wsp + off_bucket);
        int2*   binned  = (int2*)(wsp + off_binned);
        int*    fill    = (int*)(wsp + off_fill);
        int*    bin_cnt = (int*)(wsp + off_bcnt);

        hipMemsetAsync(bin_cnt, 0, BINS * sizeof(int), stream);
        part1_k<<<P1B, 256, 0, stream>>>(rows, cols, vals, bin_cnt, binned);
        part2_k<<<BINS, 256, 0, stream>>>(bin_cnt, binned, bucket, fill);
        convert_k<<<grid_elem, 256, 0, stream>>>((const float4*)x, xh, n4);

        const int grid_spmm = NI / 32;   // 3125 blocks, 32 rows each, exact
        spmm_k<0><<<grid_spmm, 256, 0, stream>>>(fill, bucket, xh,  s1h, nullptr, nullptr, nullptr);
        spmm_k<1><<<grid_spmm, 256, 0, stream>>>(fill, bucket, s1h, s2h, nullptr, nullptr, nullptr);
        spmm_k<2><<<grid_spmm, 256, 0, stream>>>(fill, bucket, s2h, nullptr, x, s1h, outp);
        return;
    }

    // ---- fallback: round-2 CSR path (fp32) ----
    const int grid_edge = (NE + 255) / 256;
    const int grid_csr  = NI / 4;

    float* bufA   = (float*)wsp;
    float* bufB   = (float*)(wsp + fbuf);
    int2*  edges  = (int2*)(wsp + 2 * fbuf);
    int*   rowptr = (int*)(wsp + 2 * fbuf + (size_t)NE * 8);
    int*   counts = rowptr + (NI + 1);
    int*   bsum   = counts + NI;

    hipMemsetAsync(counts, 0, NI * sizeof(int), stream);
    hist_k<<<grid_edge, 256, 0, stream>>>(rows, counts);
    scan1_k<<<NB, 256, 0, stream>>>(counts, bsum);
    scan2_k<<<1, 512, 0, stream>>>(bsum);
    scan3_k<<<NB, 256, 0, stream>>>(counts, bsum, rowptr);
    hipMemsetAsync(counts, 0, NI * sizeof(int), stream);
    scatter_k<<<grid_edge, 256, 0, stream>>>(rows, cols, vals, rowptr, counts, edges);
    init_k<<<grid_elem, 256, 0, stream>>>((const float4*)x, (float4*)bufA,
                                          (float4*)outp, n4);
    spmm_csr_k<<<grid_csr, 256, 0, stream>>>(rowptr, edges, bufA, bufB, outp, 0);
    spmm_csr_k<<<grid_csr, 256, 0, stream>>>(rowptr, edges, bufB, bufA, outp, 0);
    spmm_csr_k<<<grid_csr, 256, 0, stream>>>(rowptr, edges, bufA, bufB, outp, 1);
}